// Round 2
// baseline (400.782 us; speedup 1.0000x reference)
//
#include <hip/hip_runtime.h>

// NCC loss: 1 - mean( cross^2 / (pvar*tvar + 1e-8) ) over 9^3 zero-padded
// box windows, input (4,1,160,160,160) fp32.
//
// R7: R6 post-mortem showed WRITE_SIZE 50KB -> 216MB == one float4 scratch
// spill+fill per thread per step. Cause: prefetch buffers passed BY REFERENCE
// into the [&] lambda (address escape) + 40x asm "memory" clobbers -> SROA
// failure -> memory-backed locals. R7 keeps R6's mechanism (T4: lgkm-only
// barrier so the slice prefetch is never vmcnt-drained at s_barrier; depth-2
// prefetch) but the prefetch is a textual macro over named float4 locals,
// pure value semantics, zero address escape. All array indices remain
// compile-time constants (static unroll), so everything register-allocates.
// Everything else identical to R5 (register subtract-ring, stride-20 s2
// layout, double-buffered s2, one barrier per z-step).

#define DSZ    160
#define NBATCH 4
#define RAD    4
#define TX     16
#define TY     16
#define ZCHUNK 40
#define SLICE  (DSZ*DSZ)
#define VOL    (DSZ*DSZ*DSZ)
#define WINV   (1.0f/729.0f)
#define NVOX_INV (1.0f/16384000.0f)

#define NROW 24        // halo rows per tile
#define NGRP 6         // x groups of 4 halo cols (24)
#define BLK  192

#define S2_RS 20                 // row stride: 16 outputs + pad (2-way banks)
#define S2_FS (NROW*S2_RS)       // 480 floats per field
#define S2_BUF (5*S2_FS)         // 2400 floats per parity buffer

__device__ __forceinline__ float dpp_shl1(float x) {  // lane i <- lane i+1 (16-lane row, OOB=0)
    return __int_as_float(__builtin_amdgcn_update_dpp(0, __float_as_int(x), 0x101, 0xf, 0xf, true));
}
__device__ __forceinline__ float dpp_shl2(float x) {  // lane i <- lane i+2
    return __int_as_float(__builtin_amdgcn_update_dpp(0, __float_as_int(x), 0x102, 0xf, 0xf, true));
}

__global__ __launch_bounds__(BLK, 3)
void ncc_main(const float* __restrict__ pred, const float* __restrict__ tgt,
              float* __restrict__ accum)
{
    const int tid = threadIdx.x;
    const int row = tid >> 3;      // 0..23 halo row
    const int g   = tid & 7;       // 0..7; g<6 = active x-group
    const int ox  = blockIdx.x * TX;
    const int oy  = blockIdx.y * TY;
    const int batch = blockIdx.z >> 2;
    const int z0  = (blockIdx.z & 3) * ZCHUNK;

    __shared__ float s2[2*S2_BUF];   // 19.2 KB, double-buffered [f][y][x pad20]

    const bool stg = (g < NGRP);
    const int  gy  = oy - RAD + row;
    const int  gx0 = ox - RAD + g*4;
    const bool ldok = stg && (gy >= 0) && (gy < DSZ) && (gx0 >= 0) && (gx0 + 3 < DSZ);
    const int  base = batch*VOL + gy*DSZ + gx0;     // only used under ldok

    // register ring of raw slice values (own 4 columns), chunk-local slots
    float rp[9][4], rt[9][4];
    float zs[5][4];
    #pragma unroll
    for (int k = 0; k < 9; ++k)
        #pragma unroll
        for (int j = 0; j < 4; ++j) { rp[k][j] = 0.f; rt[k][j] = 0.f; }
    #pragma unroll
    for (int f = 0; f < 5; ++f)
        #pragma unroll
        for (int j = 0; j < 4; ++j) zs[f][j] = 0.f;

    // ---- warm-up: chunk-local slices 0..7 (z = z0-4 .. z0+3) -> slots 0..7
    #pragma unroll
    for (int i = 0; i < 8; ++i) {
        int z = z0 - RAD + i;
        if (z >= 0) {                       // uniform; z < DSZ always here
            float4 p4 = {0,0,0,0}, t4 = {0,0,0,0};
            if (ldok) {
                p4 = *(const float4*)(pred + base + z*SLICE);
                t4 = *(const float4*)(tgt  + base + z*SLICE);
            }
            const float pc[4] = {p4.x,p4.y,p4.z,p4.w};
            const float tc[4] = {t4.x,t4.y,t4.z,t4.w};
            #pragma unroll
            for (int j = 0; j < 4; ++j) {
                zs[0][j] += pc[j];        zs[1][j] += tc[j];
                zs[2][j] += pc[j]*pc[j];  zs[3][j] += tc[j]*tc[j];
                zs[4][j] += pc[j]*tc[j];
                rp[i][j] = pc[j];  rt[i][j] = tc[j];
            }
        }
    }

    // ---- streaming prefetch, depth 2: slices s and s+1 in flight ----
    // Pure value semantics: no lambda, no references, no address escape.
    int za = z0 + RAD;                      // absolute z of next fetch
    int zmax = z0 + ZCHUNK + RAD;           // last useful slice + 1
    if (zmax > DSZ) zmax = DSZ;
    float4 pA = {0,0,0,0}, tA = {0,0,0,0};  // even steps
    float4 pB = {0,0,0,0}, tB = {0,0,0,0};  // odd steps

#define PF_INTO(PD, TD) do {                                                  \
    float4 _p = {0,0,0,0}, _t = {0,0,0,0};                                    \
    if (ldok && za < zmax) {                                                  \
        _p = *(const float4*)(pred + base + za*SLICE);                        \
        _t = *(const float4*)(tgt  + base + za*SLICE);                        \
    }                                                                         \
    PD = _p; TD = _t; ++za;                                                   \
} while (0)

    PF_INTO(pA, tA);     // slice for step 0
    PF_INTO(pB, tB);     // slice for step 1

    int pb = 1;          // parity buffer toggle (first step -> 0)
    float acc = 0.f;

#define NCC_STEP(SLOT, PBUF, TBUF) do {                                       \
    pb ^= 1;                                                                  \
    float* s2w = s2 + pb*S2_BUF;                                              \
    if (stg) {                                                                \
        const float pc[4] = {PBUF.x, PBUF.y, PBUF.z, PBUF.w};                 \
        const float tc[4] = {TBUF.x, TBUF.y, TBUF.z, TBUF.w};                 \
        PF_INTO(PBUF, TBUF);  /* issue slice s+2; survives the barrier */     \
        _Pragma("unroll")                                                     \
        for (int j = 0; j < 4; ++j) {                                         \
            float ps = rp[SLOT][j], qs = rt[SLOT][j];                         \
            float d0 = pc[j] - ps, d1 = tc[j] - qs;                           \
            zs[0][j] += d0;                                                   \
            zs[1][j] += d1;                                                   \
            zs[2][j] += d0*(pc[j] + ps);                                      \
            zs[3][j] += d1*(tc[j] + qs);                                      \
            zs[4][j] += pc[j]*tc[j] - ps*qs;                                  \
            rp[SLOT][j] = pc[j];  rt[SLOT][j] = tc[j];                        \
        }                                                                     \
        _Pragma("unroll")                                                     \
        for (int f = 0; f < 5; ++f) {                                         \
            float P0 = zs[f][0];                                              \
            float P1 = P0 + zs[f][1];                                         \
            float P2 = P1 + zs[f][2];                                         \
            float P3 = P2 + zs[f][3];                                         \
            float T  = dpp_shl1(P3);                                          \
            float Q0 = dpp_shl2(P0), Q1 = dpp_shl2(P1);                       \
            float Q2 = dpp_shl2(P2), Q3 = dpp_shl2(P3);                       \
            if (g < 4) {                                                      \
                float b = P3 + T;                                             \
                float* dst = &s2w[f*S2_FS + row*S2_RS + g*4];                 \
                dst[0] = b + Q0;                                              \
                dst[1] = b - P0 + Q1;                                         \
                dst[2] = b - P1 + Q2;                                         \
                dst[3] = b - P2 + Q3;                                         \
            }                                                                 \
        }                                                                     \
    }                                                                         \
    /* lgkm-only barrier: ds ops drained, global prefetch stays in flight */  \
    asm volatile("s_waitcnt lgkmcnt(0)" ::: "memory");                        \
    __builtin_amdgcn_s_barrier();                                             \
    asm volatile("" ::: "memory");                                            \
    if (tid < 64) {                                                           \
        const int x = tid & 15, yq = (tid >> 4)*4;                            \
        float S[5][4];                                                        \
        _Pragma("unroll")                                                     \
        for (int f = 0; f < 5; ++f) {                                         \
            const float* col = &s2w[f*S2_FS + x];                             \
            float r0 = col[(yq+0)*S2_RS], r1 = col[(yq+1)*S2_RS];             \
            float r2 = col[(yq+2)*S2_RS], r3 = col[(yq+3)*S2_RS];             \
            float run = r0+r1+r2+r3 + col[(yq+4)*S2_RS] + col[(yq+5)*S2_RS]   \
                      + col[(yq+6)*S2_RS] + col[(yq+7)*S2_RS];                \
            run += col[(yq+8)*S2_RS];        S[f][0] = run;                   \
            run += col[(yq+9)*S2_RS]  - r0;  S[f][1] = run;                   \
            run += col[(yq+10)*S2_RS] - r1;  S[f][2] = run;                   \
            run += col[(yq+11)*S2_RS] - r2;  S[f][3] = run;                   \
        }                                                                     \
        _Pragma("unroll")                                                     \
        for (int i = 0; i < 4; ++i) {                                         \
            float Sp = S[0][i], St = S[1][i];                                 \
            float cross = S[4][i] - Sp*St*WINV;                               \
            float pv    = S[2][i] - Sp*Sp*WINV;                               \
            float tv    = S[3][i] - St*St*WINV;                               \
            acc += cross*cross / (pv*tv + 1e-8f);                             \
        }                                                                     \
    }                                                                         \
} while (0)

    // steps s=0..3: slots (s+8)%9 = 8,0,1,2 ; buffers A,B,A,B
    NCC_STEP(8,pA,tA); NCC_STEP(0,pB,tB); NCC_STEP(1,pA,tA); NCC_STEP(2,pB,tB);
    // steps s=4..39: slot sequence 9-periodic, buffer parity 2-periodic ->
    // 18-step body (lcm) repeated twice keeps every index compile-time static.
    for (int it = 0; it < 2; ++it) {
        NCC_STEP(3,pA,tA); NCC_STEP(4,pB,tB); NCC_STEP(5,pA,tA);
        NCC_STEP(6,pB,tB); NCC_STEP(7,pA,tA); NCC_STEP(8,pB,tB);
        NCC_STEP(0,pA,tA); NCC_STEP(1,pB,tB); NCC_STEP(2,pA,tA);
        NCC_STEP(3,pB,tB); NCC_STEP(4,pA,tA); NCC_STEP(5,pB,tB);
        NCC_STEP(6,pA,tA); NCC_STEP(7,pB,tB); NCC_STEP(8,pA,tA);
        NCC_STEP(0,pB,tB); NCC_STEP(1,pA,tA); NCC_STEP(2,pB,tB);
    }
#undef NCC_STEP
#undef PF_INTO

    // all cc partials live in wave 0
    if (tid < 64) {
        float v = acc;
        #pragma unroll
        for (int off = 32; off > 0; off >>= 1) v += __shfl_down(v, off, 64);
        if (tid == 0) atomicAdd(accum, v);
    }
}

__global__ void ncc_final(const float* __restrict__ accum, float* __restrict__ out)
{
    out[0] = 1.0f - accum[0] * NVOX_INV;
}

extern "C" void kernel_launch(void* const* d_in, const int* in_sizes, int n_in,
                              void* d_out, int out_size, void* d_ws, size_t ws_size,
                              hipStream_t stream)
{
    const float* pred = (const float*)d_in[0];
    const float* tgt  = (const float*)d_in[1];
    float* out = (float*)d_out;
    float* ws  = (float*)d_ws;

    hipMemsetAsync(ws, 0, sizeof(float), stream);
    dim3 grid(DSZ/TX, DSZ/TY, NBATCH*4);   // 10 x 10 x 16 = 1600 blocks
    ncc_main<<<grid, BLK, 0, stream>>>(pred, tgt, ws);
    ncc_final<<<1, 1, 0, stream>>>(ws, out);
}

// Round 3
// 229.982 us; speedup vs baseline: 1.7427x; 1.7427x over previous
//
#include <hip/hip_runtime.h>

// NCC loss: 1 - mean( cross^2 / (pvar*tvar + 1e-8) ) over 9^3 zero-padded
// box windows, input (4,1,160,160,160) fp32.
//
// R8: R6/R7 post-mortem — 216MB WRITE_SIZE was REGISTER-ALLOCATOR SPILL
// (pressure: depth-2 prefetch +16 VGPR and 18-step scheduled body pushed
// combined VGPR+AGPR past the 168/wave budget of launch_bounds(192,3); spill
// ~4 floats/step = 17.6B/thread/step = 216MB). Not SROA, not the lambda.
// R8 = R5 structure verbatim (depth-1 prefetch pa4/ta4, 9-step periodic
// body, identical register footprint) with ONE change: __syncthreads()
// replaced by lgkm-only barrier (s_waitcnt lgkmcnt(0) + raw s_barrier), so
// the slice prefetch — issued at the top of each step, right after its
// consumer copy — stays in flight across the barrier (T4) instead of being
// vmcnt(0)-drained. Only remaining vmcnt wait is the compiler's counted wait
// at the consume point one full step later.

#define DSZ    160
#define NBATCH 4
#define RAD    4
#define TX     16
#define TY     16
#define ZCHUNK 40
#define SLICE  (DSZ*DSZ)
#define VOL    (DSZ*DSZ*DSZ)
#define WINV   (1.0f/729.0f)
#define NVOX_INV (1.0f/16384000.0f)

#define NROW 24        // halo rows per tile
#define NGRP 6         // x groups of 4 halo cols (24)
#define BLK  192

#define S2_RS 20                 // row stride: 16 outputs + pad (2-way banks)
#define S2_FS (NROW*S2_RS)       // 480 floats per field
#define S2_BUF (5*S2_FS)         // 2400 floats per parity buffer

__device__ __forceinline__ float dpp_shl1(float x) {  // lane i <- lane i+1 (16-lane row, OOB=0)
    return __int_as_float(__builtin_amdgcn_update_dpp(0, __float_as_int(x), 0x101, 0xf, 0xf, true));
}
__device__ __forceinline__ float dpp_shl2(float x) {  // lane i <- lane i+2
    return __int_as_float(__builtin_amdgcn_update_dpp(0, __float_as_int(x), 0x102, 0xf, 0xf, true));
}

__global__ __launch_bounds__(BLK, 3)
void ncc_main(const float* __restrict__ pred, const float* __restrict__ tgt,
              float* __restrict__ accum)
{
    const int tid = threadIdx.x;
    const int row = tid >> 3;      // 0..23 halo row
    const int g   = tid & 7;       // 0..7; g<6 = active x-group
    const int ox  = blockIdx.x * TX;
    const int oy  = blockIdx.y * TY;
    const int batch = blockIdx.z >> 2;
    const int z0  = (blockIdx.z & 3) * ZCHUNK;

    __shared__ float s2[2*S2_BUF];   // 19.2 KB, double-buffered [f][y][x pad20]

    const bool stg = (g < NGRP);
    const int  gy  = oy - RAD + row;
    const int  gx0 = ox - RAD + g*4;
    const bool ldok = stg && (gy >= 0) && (gy < DSZ) && (gx0 >= 0) && (gx0 + 3 < DSZ);
    const int  base = batch*VOL + gy*DSZ + gx0;     // only used under ldok

    // register ring of raw slice values (own 4 columns), chunk-local slots
    float rp[9][4], rt[9][4];
    float zs[5][4];
    #pragma unroll
    for (int k = 0; k < 9; ++k)
        #pragma unroll
        for (int j = 0; j < 4; ++j) { rp[k][j] = 0.f; rt[k][j] = 0.f; }
    #pragma unroll
    for (int f = 0; f < 5; ++f)
        #pragma unroll
        for (int j = 0; j < 4; ++j) zs[f][j] = 0.f;

    // ---- warm-up: chunk-local slices 0..7 (z = z0-4 .. z0+3) -> slots 0..7
    #pragma unroll
    for (int i = 0; i < 8; ++i) {
        int z = z0 - RAD + i;
        if (z >= 0) {                       // uniform; z < DSZ always here
            float4 p4 = {0,0,0,0}, t4 = {0,0,0,0};
            if (ldok) {
                p4 = *(const float4*)(pred + base + z*SLICE);
                t4 = *(const float4*)(tgt  + base + z*SLICE);
            }
            const float pc[4] = {p4.x,p4.y,p4.z,p4.w};
            const float tc[4] = {t4.x,t4.y,t4.z,t4.w};
            #pragma unroll
            for (int j = 0; j < 4; ++j) {
                zs[0][j] += pc[j];        zs[1][j] += tc[j];
                zs[2][j] += pc[j]*pc[j];  zs[3][j] += tc[j]*tc[j];
                zs[4][j] += pc[j]*tc[j];
                rp[i][j] = pc[j];  rt[i][j] = tc[j];
            }
        }
    }

    // ---- streaming prefetch of the next add-slice (depth 1, like R5) ----
    int za = z0 + RAD;                      // absolute z of next fetch
    int zmax = z0 + ZCHUNK + RAD;           // last useful slice + 1
    if (zmax > DSZ) zmax = DSZ;
    float4 pa4 = {0,0,0,0}, ta4 = {0,0,0,0};

#define PF_NEXT() do {                                                        \
    float4 _p = {0,0,0,0}, _t = {0,0,0,0};                                    \
    if (ldok && za < zmax) {                                                  \
        _p = *(const float4*)(pred + base + za*SLICE);                        \
        _t = *(const float4*)(tgt  + base + za*SLICE);                        \
    }                                                                         \
    pa4 = _p; ta4 = _t; ++za;                                                 \
} while (0)

    PF_NEXT();           // slice for step 0

    int pb = 1;          // parity buffer toggle (first step -> 0)
    float acc = 0.f;

#define NCC_STEP(SLOT) do {                                                   \
    pb ^= 1;                                                                  \
    float* s2w = s2 + pb*S2_BUF;                                              \
    if (stg) {                                                                \
        const float pc[4] = {pa4.x,pa4.y,pa4.z,pa4.w};                        \
        const float tc[4] = {ta4.x,ta4.y,ta4.z,ta4.w};                        \
        PF_NEXT();  /* issue slice s+1 now; it stays in flight across the */  \
                    /* barrier (lgkm-only) and is vmcnt-waited next step  */  \
        _Pragma("unroll")                                                     \
        for (int j = 0; j < 4; ++j) {                                         \
            float ps = rp[SLOT][j], qs = rt[SLOT][j];                         \
            float d0 = pc[j] - ps, d1 = tc[j] - qs;                           \
            zs[0][j] += d0;                                                   \
            zs[1][j] += d1;                                                   \
            zs[2][j] += d0*(pc[j] + ps);                                      \
            zs[3][j] += d1*(tc[j] + qs);                                      \
            zs[4][j] += pc[j]*tc[j] - ps*qs;                                  \
            rp[SLOT][j] = pc[j];  rt[SLOT][j] = tc[j];                        \
        }                                                                     \
        _Pragma("unroll")                                                     \
        for (int f = 0; f < 5; ++f) {                                         \
            float P0 = zs[f][0];                                              \
            float P1 = P0 + zs[f][1];                                         \
            float P2 = P1 + zs[f][2];                                         \
            float P3 = P2 + zs[f][3];                                         \
            float T  = dpp_shl1(P3);                                          \
            float Q0 = dpp_shl2(P0), Q1 = dpp_shl2(P1);                       \
            float Q2 = dpp_shl2(P2), Q3 = dpp_shl2(P3);                       \
            if (g < 4) {                                                      \
                float b = P3 + T;                                             \
                float* dst = &s2w[f*S2_FS + row*S2_RS + g*4];                 \
                dst[0] = b + Q0;                                              \
                dst[1] = b - P0 + Q1;                                         \
                dst[2] = b - P1 + Q2;                                         \
                dst[3] = b - P2 + Q3;                                         \
            }                                                                 \
        }                                                                     \
    }                                                                         \
    /* lgkm-only barrier: own ds_writes drained, prefetch stays in flight */  \
    asm volatile("s_waitcnt lgkmcnt(0)" ::: "memory");                        \
    __builtin_amdgcn_s_barrier();                                             \
    asm volatile("" ::: "memory");                                            \
    if (tid < 64) {                                                           \
        const int x = tid & 15, yq = (tid >> 4)*4;                            \
        float S[5][4];                                                        \
        _Pragma("unroll")                                                     \
        for (int f = 0; f < 5; ++f) {                                         \
            const float* col = &s2w[f*S2_FS + x];                             \
            float r0 = col[(yq+0)*S2_RS], r1 = col[(yq+1)*S2_RS];             \
            float r2 = col[(yq+2)*S2_RS], r3 = col[(yq+3)*S2_RS];             \
            float run = r0+r1+r2+r3 + col[(yq+4)*S2_RS] + col[(yq+5)*S2_RS]   \
                      + col[(yq+6)*S2_RS] + col[(yq+7)*S2_RS];                \
            run += col[(yq+8)*S2_RS];        S[f][0] = run;                   \
            run += col[(yq+9)*S2_RS]  - r0;  S[f][1] = run;                   \
            run += col[(yq+10)*S2_RS] - r1;  S[f][2] = run;                   \
            run += col[(yq+11)*S2_RS] - r2;  S[f][3] = run;                   \
        }                                                                     \
        _Pragma("unroll")                                                     \
        for (int i = 0; i < 4; ++i) {                                         \
            float Sp = S[0][i], St = S[1][i];                                 \
            float cross = S[4][i] - Sp*St*WINV;                               \
            float pv    = S[2][i] - Sp*Sp*WINV;                               \
            float tv    = S[3][i] - St*St*WINV;                               \
            acc += cross*cross / (pv*tv + 1e-8f);                             \
        }                                                                     \
    }                                                                         \
} while (0)

    // steps s=0..3: slots (s+8)%9 = 8,0,1,2
    NCC_STEP(8); NCC_STEP(0); NCC_STEP(1); NCC_STEP(2);
    // steps s=4..39: slot sequence (s+8)%9 is 9-periodic: 3,4,5,6,7,8,0,1,2
    for (int it = 0; it < 4; ++it) {
        NCC_STEP(3); NCC_STEP(4); NCC_STEP(5);
        NCC_STEP(6); NCC_STEP(7); NCC_STEP(8);
        NCC_STEP(0); NCC_STEP(1); NCC_STEP(2);
    }
#undef NCC_STEP
#undef PF_NEXT

    // all cc partials live in wave 0
    if (tid < 64) {
        float v = acc;
        #pragma unroll
        for (int off = 32; off > 0; off >>= 1) v += __shfl_down(v, off, 64);
        if (tid == 0) atomicAdd(accum, v);
    }
}

__global__ void ncc_final(const float* __restrict__ accum, float* __restrict__ out)
{
    out[0] = 1.0f - accum[0] * NVOX_INV;
}

extern "C" void kernel_launch(void* const* d_in, const int* in_sizes, int n_in,
                              void* d_out, int out_size, void* d_ws, size_t ws_size,
                              hipStream_t stream)
{
    const float* pred = (const float*)d_in[0];
    const float* tgt  = (const float*)d_in[1];
    float* out = (float*)d_out;
    float* ws  = (float*)d_ws;

    hipMemsetAsync(ws, 0, sizeof(float), stream);
    dim3 grid(DSZ/TX, DSZ/TY, NBATCH*4);   // 10 x 10 x 16 = 1600 blocks
    ncc_main<<<grid, BLK, 0, stream>>>(pred, tgt, ws);
    ncc_final<<<1, 1, 0, stream>>>(ws, out);
}

// Round 4
// 223.667 us; speedup vs baseline: 1.7919x; 1.0282x over previous
//
#include <hip/hip_runtime.h>

// NCC loss: 1 - mean( cross^2 / (pvar*tvar + 1e-8) ) over 9^3 zero-padded
// box windows, input (4,1,160,160,160) fp32.
//
// R9: R8 refuted the barrier-drain theory (lgkm-only barrier = -23%: inline
// asm defeats waitcnt/scheduling; __syncthreads restored). Remaining stall is
// the WAVE-0 CONVOY: per step, all waves stage s2 -> barrier -> wave 0 alone
// runs the 60-ds_read column reduction, THEN starts its next staging. Block
// period = stg + reduction, serial in wave 0, while waves 1,2 park at the
// barrier. R9 = R5 verbatim except BLK 192->256: new wave 3 (64 lanes) is a
// DEDICATED reduction wave. After each barrier, wave 3 reduces buffer pb
// while waves 0-2 write pb^1 (the existing double-buffer protocol already
// permits exactly this overlap; buffer X is rewritten only after the next
// barrier, which wave 3 cannot pass before issuing its reads). Period ->
// max(stg, red). Same register state, 3 blocks/CU x 4 waves = 12 waves/CU.

#define DSZ    160
#define NBATCH 4
#define RAD    4
#define TX     16
#define TY     16
#define ZCHUNK 40
#define SLICE  (DSZ*DSZ)
#define VOL    (DSZ*DSZ*DSZ)
#define WINV   (1.0f/729.0f)
#define NVOX_INV (1.0f/16384000.0f)

#define NROW 24        // halo rows per tile
#define NGRP 6         // x groups of 4 halo cols (24)
#define BLK  256       // 3 staging waves (tid<192) + 1 reduction wave

#define S2_RS 20                 // row stride: 16 outputs + pad (2-way banks)
#define S2_FS (NROW*S2_RS)       // 480 floats per field
#define S2_BUF (5*S2_FS)         // 2400 floats per parity buffer

__device__ __forceinline__ float dpp_shl1(float x) {  // lane i <- lane i+1 (16-lane row, OOB=0)
    return __int_as_float(__builtin_amdgcn_update_dpp(0, __float_as_int(x), 0x101, 0xf, 0xf, true));
}
__device__ __forceinline__ float dpp_shl2(float x) {  // lane i <- lane i+2
    return __int_as_float(__builtin_amdgcn_update_dpp(0, __float_as_int(x), 0x102, 0xf, 0xf, true));
}

__global__ __launch_bounds__(BLK, 3)
void ncc_main(const float* __restrict__ pred, const float* __restrict__ tgt,
              float* __restrict__ accum)
{
    const int tid = threadIdx.x;
    const int row = tid >> 3;      // 0..23 halo row (staging threads)
    const int g   = tid & 7;       // 0..7; g<6 = active x-group
    const int ox  = blockIdx.x * TX;
    const int oy  = blockIdx.y * TY;
    const int batch = blockIdx.z >> 2;
    const int z0  = (blockIdx.z & 3) * ZCHUNK;

    __shared__ float s2[2*S2_BUF];   // 19.2 KB, double-buffered [f][y][x pad20]

    const bool stg = (tid < 192) && (g < NGRP);
    const bool red = (tid >= 192);               // dedicated reduction wave
    const int  gy  = oy - RAD + row;
    const int  gx0 = ox - RAD + g*4;
    const bool ldok = stg && (gy >= 0) && (gy < DSZ) && (gx0 >= 0) && (gx0 + 3 < DSZ);
    const int  base = batch*VOL + gy*DSZ + gx0;     // only used under ldok

    // register ring of raw slice values (own 4 columns), chunk-local slots
    float rp[9][4], rt[9][4];
    float zs[5][4];
    #pragma unroll
    for (int k = 0; k < 9; ++k)
        #pragma unroll
        for (int j = 0; j < 4; ++j) { rp[k][j] = 0.f; rt[k][j] = 0.f; }
    #pragma unroll
    for (int f = 0; f < 5; ++f)
        #pragma unroll
        for (int j = 0; j < 4; ++j) zs[f][j] = 0.f;

    // ---- warm-up: chunk-local slices 0..7 (z = z0-4 .. z0+3) -> slots 0..7
    if (stg) {
        #pragma unroll
        for (int i = 0; i < 8; ++i) {
            int z = z0 - RAD + i;
            if (z >= 0) {                       // uniform; z < DSZ always here
                float4 p4 = {0,0,0,0}, t4 = {0,0,0,0};
                if (ldok) {
                    p4 = *(const float4*)(pred + base + z*SLICE);
                    t4 = *(const float4*)(tgt  + base + z*SLICE);
                }
                const float pc[4] = {p4.x,p4.y,p4.z,p4.w};
                const float tc[4] = {t4.x,t4.y,t4.z,t4.w};
                #pragma unroll
                for (int j = 0; j < 4; ++j) {
                    zs[0][j] += pc[j];        zs[1][j] += tc[j];
                    zs[2][j] += pc[j]*pc[j];  zs[3][j] += tc[j]*tc[j];
                    zs[4][j] += pc[j]*tc[j];
                    rp[i][j] = pc[j];  rt[i][j] = tc[j];
                }
            }
        }
    }

    // ---- streaming prefetch of the next add-slice (depth 1) ----
    int za = z0 + RAD;                      // absolute z of next fetch
    int zmax = z0 + ZCHUNK + RAD;           // last useful slice + 1
    if (zmax > DSZ) zmax = DSZ;
    float4 pa4 = {0,0,0,0}, ta4 = {0,0,0,0};

#define PF_NEXT() do {                                                        \
    float4 _p = {0,0,0,0}, _t = {0,0,0,0};                                    \
    if (ldok && za < zmax) {                                                  \
        _p = *(const float4*)(pred + base + za*SLICE);                        \
        _t = *(const float4*)(tgt  + base + za*SLICE);                        \
    }                                                                         \
    pa4 = _p; ta4 = _t; ++za;                                                 \
} while (0)

    if (stg) PF_NEXT();  // slice for step 0

    int pb = 1;          // parity buffer toggle (first step -> 0)
    float acc = 0.f;

#define NCC_STEP(SLOT) do {                                                   \
    pb ^= 1;                                                                  \
    float* s2w = s2 + pb*S2_BUF;                                              \
    if (stg) {                                                                \
        const float pc[4] = {pa4.x,pa4.y,pa4.z,pa4.w};                        \
        const float tc[4] = {ta4.x,ta4.y,ta4.z,ta4.w};                        \
        PF_NEXT();  /* issue slice s+1; drains at this step's barrier */      \
        _Pragma("unroll")                                                     \
        for (int j = 0; j < 4; ++j) {                                         \
            float ps = rp[SLOT][j], qs = rt[SLOT][j];                         \
            float d0 = pc[j] - ps, d1 = tc[j] - qs;                           \
            zs[0][j] += d0;                                                   \
            zs[1][j] += d1;                                                   \
            zs[2][j] += d0*(pc[j] + ps);                                      \
            zs[3][j] += d1*(tc[j] + qs);                                      \
            zs[4][j] += pc[j]*tc[j] - ps*qs;                                  \
            rp[SLOT][j] = pc[j];  rt[SLOT][j] = tc[j];                        \
        }                                                                     \
        _Pragma("unroll")                                                     \
        for (int f = 0; f < 5; ++f) {                                         \
            float P0 = zs[f][0];                                              \
            float P1 = P0 + zs[f][1];                                         \
            float P2 = P1 + zs[f][2];                                         \
            float P3 = P2 + zs[f][3];                                         \
            float T  = dpp_shl1(P3);                                          \
            float Q0 = dpp_shl2(P0), Q1 = dpp_shl2(P1);                       \
            float Q2 = dpp_shl2(P2), Q3 = dpp_shl2(P3);                       \
            if (g < 4) {                                                      \
                float b = P3 + T;                                             \
                float* dst = &s2w[f*S2_FS + row*S2_RS + g*4];                 \
                dst[0] = b + Q0;                                              \
                dst[1] = b - P0 + Q1;                                         \
                dst[2] = b - P1 + Q2;                                         \
                dst[3] = b - P2 + Q3;                                         \
            }                                                                 \
        }                                                                     \
    }                                                                         \
    __syncthreads();                                                          \
    if (red) {                                                                \
        const int x = tid & 15, yq = ((tid >> 4) & 3)*4;                      \
        float S[5][4];                                                        \
        _Pragma("unroll")                                                     \
        for (int f = 0; f < 5; ++f) {                                         \
            const float* col = &s2w[f*S2_FS + x];                             \
            float r0 = col[(yq+0)*S2_RS], r1 = col[(yq+1)*S2_RS];             \
            float r2 = col[(yq+2)*S2_RS], r3 = col[(yq+3)*S2_RS];             \
            float run = r0+r1+r2+r3 + col[(yq+4)*S2_RS] + col[(yq+5)*S2_RS]   \
                      + col[(yq+6)*S2_RS] + col[(yq+7)*S2_RS];                \
            run += col[(yq+8)*S2_RS];        S[f][0] = run;                   \
            run += col[(yq+9)*S2_RS]  - r0;  S[f][1] = run;                   \
            run += col[(yq+10)*S2_RS] - r1;  S[f][2] = run;                   \
            run += col[(yq+11)*S2_RS] - r2;  S[f][3] = run;                   \
        }                                                                     \
        _Pragma("unroll")                                                     \
        for (int i = 0; i < 4; ++i) {                                         \
            float Sp = S[0][i], St = S[1][i];                                 \
            float cross = S[4][i] - Sp*St*WINV;                               \
            float pv    = S[2][i] - Sp*Sp*WINV;                               \
            float tv    = S[3][i] - St*St*WINV;                               \
            acc += cross*cross / (pv*tv + 1e-8f);                             \
        }                                                                     \
    }                                                                         \
} while (0)

    // steps s=0..3: slots (s+8)%9 = 8,0,1,2
    NCC_STEP(8); NCC_STEP(0); NCC_STEP(1); NCC_STEP(2);
    // steps s=4..39: slot sequence (s+8)%9 is 9-periodic: 3,4,5,6,7,8,0,1,2
    for (int it = 0; it < 4; ++it) {
        NCC_STEP(3); NCC_STEP(4); NCC_STEP(5);
        NCC_STEP(6); NCC_STEP(7); NCC_STEP(8);
        NCC_STEP(0); NCC_STEP(1); NCC_STEP(2);
    }
#undef NCC_STEP
#undef PF_NEXT

    // all cc partials live in the reduction wave (tid 192..255)
    if (red) {
        float v = acc;
        #pragma unroll
        for (int off = 32; off > 0; off >>= 1) v += __shfl_down(v, off, 64);
        if (tid == 192) atomicAdd(accum, v);
    }
}

__global__ void ncc_final(const float* __restrict__ accum, float* __restrict__ out)
{
    out[0] = 1.0f - accum[0] * NVOX_INV;
}

extern "C" void kernel_launch(void* const* d_in, const int* in_sizes, int n_in,
                              void* d_out, int out_size, void* d_ws, size_t ws_size,
                              hipStream_t stream)
{
    const float* pred = (const float*)d_in[0];
    const float* tgt  = (const float*)d_in[1];
    float* out = (float*)d_out;
    float* ws  = (float*)d_ws;

    hipMemsetAsync(ws, 0, sizeof(float), stream);
    dim3 grid(DSZ/TX, DSZ/TY, NBATCH*4);   // 10 x 10 x 16 = 1600 blocks
    ncc_main<<<grid, BLK, 0, stream>>>(pred, tgt, ws);
    ncc_final<<<1, 1, 0, stream>>>(ws, out);
}